// Round 13
// baseline (72.136 us; speedup 1.0000x reference)
//
#include <hip/hip_runtime.h>

// NCF fused forward, v13: single prep launch (user rows VALU + weight transposes)
// + v12 main (64 pairs/block fp8 tower, swapped GEMMs, 3 barriers) unchanged.

typedef __attribute__((ext_vector_type(8))) short bf16x8;
typedef __attribute__((ext_vector_type(4))) float f32x4;

__device__ __forceinline__ unsigned char f2fp8(float x){
  return (unsigned char)(__builtin_amdgcn_cvt_pk_fp8_f32(x, 0.f, 0, false) & 0xFF);
}

// ws layout (bytes):
//   0      W1iT fp8 [128][64]   (8192)
//   8192   W2T  fp8 [64][128]   (8192)
//   16384  W3T  fp8 [32][64]    (2048)
//   18432  Xu   f32 [B][128];  then wup f32 [B][64];  cu f32 [B]

// ---- prep: blocks 0..B-1 = per-user; blocks B..B+143 = weight transposes ----
__global__ __launch_bounds__(128) void ncf_prep(
    const int* __restrict__ user,
    const float* __restrict__ Wu_gmf, const float* __restrict__ bu_gmf,
    const float* __restrict__ Wu_mlp, const float* __restrict__ bu_mlp,
    const float* __restrict__ bi_gmf, const float* __restrict__ bi_mlp,
    const float* __restrict__ W1, const float* __restrict__ b1,
    const float* __restrict__ W2, const float* __restrict__ W3,
    const float* __restrict__ Wp,
    unsigned char* __restrict__ wsT, float* __restrict__ Xu,
    float* __restrict__ wup, float* __restrict__ cu, int B)
{
  int bid = blockIdx.x;
  int j = threadIdx.x;
  if (bid < B){
    long u = (long)user[bid];
    float acc = b1[j];
    #pragma unroll 4
    for (int k = 0; k < 64; k++){
      float eu = Wu_mlp[u*64 + k] + bu_mlp[k];
      acc += eu * W1[k*128 + j] + bi_mlp[k] * W1[(64 + k)*128 + j];
    }
    Xu[(long)bid*128 + j] = acc;
    if (j < 64){
      float wg = (Wu_gmf[u*64 + j] + bu_gmf[j]) * Wp[j];
      wup[(long)bid*64 + j] = wg;
      float c = wg * bi_gmf[j];
      c += __shfl_xor(c, 1);  c += __shfl_xor(c, 2);
      c += __shfl_xor(c, 4);  c += __shfl_xor(c, 8);
      c += __shfl_xor(c, 16); c += __shfl_xor(c, 32);
      if (j == 0) cu[bid] = c;
    }
    return;
  }
  int i = (bid - B)*128 + j;                      // 0..18431
  if (i < 8192){                                  // W1iT fp8 [col][k] = W1[64+k][col]
    int col = i >> 6, k = i & 63;
    wsT[i] = f2fp8(W1[(64 + k)*128 + col]);
  } else if (i < 16384){                          // W2T fp8 [col][k] = W2[k][col]
    int t = i - 8192; int col = t >> 7, k = t & 127;
    wsT[i] = f2fp8(W2[k*64 + col]);
  } else {                                        // W3T fp8 [col][k] = W3[k][col]
    int t = i - 16384; int col = (t - 0) >> 6, k = t & 63;
    wsT[i] = f2fp8(W3[k*32 + col]);
  }
}

// ---- main: v12 structure, unchanged ----
__global__ __launch_bounds__(256, 6) void ncf_main(
    const int* __restrict__ item,
    const float* __restrict__ Wi_mlp, const float* __restrict__ Wi_gmf,
    const unsigned char* __restrict__ W1iT, const unsigned char* __restrict__ W2T,
    const unsigned char* __restrict__ W3T,
    const float* __restrict__ b2, const float* __restrict__ b3,
    const float* __restrict__ Wp, const float* __restrict__ bp,
    const float* __restrict__ Xu, const float* __restrict__ wup,
    const float* __restrict__ cu,
    float* __restrict__ out, int N, int total, int Bsz)
{
  __shared__ __align__(16) unsigned char s_item[64][80];  // item mlp rows, fp8
  __shared__ __align__(16) unsigned char s_h1[64][136];   // h1 fp8
  __shared__ __align__(16) unsigned char s_h2[64][80];    // h2 fp8
  __shared__ __align__(16) float s_xu[2][128];
  __shared__            float s_pg[64];

  const int tid = threadIdx.x;
  const int p0  = blockIdx.x * 64;
  const int b0  = p0 / N;
  const int thr = (b0 + 1) * N;
  const int r   = tid >> 2, q = tid & 3;
  const int w   = tid >> 6, l = tid & 63;
  const int lr  = l & 15,  lg = l >> 4;
  const float bp0 = bp[0];

  // ---- store: item mlp row -> fp8 LDS; pg dot; Xu -> LDS ----
  {
    int p = p0 + r;
    int b = b0 + ((p >= thr) ? 1 : 0);
    long ib = (long)item[p] * 64;
    const float4* mp = (const float4*)(Wi_mlp + ib) + q*4;
    const float4* gp = (const float4*)(Wi_gmf + ib) + q*4;
    const float4* wq = (const float4*)(wup + (long)b*64) + q*4;
    float pg = 0.f;
    int pk[4];
    #pragma unroll
    for (int j = 0; j < 4; j++){
      float4 m = mp[j], g = gp[j], wv = wq[j];
      pg += g.x*wv.x + g.y*wv.y + g.z*wv.z + g.w*wv.w;
      int t_ = __builtin_amdgcn_cvt_pk_fp8_f32(m.x, m.y, 0, false);
      t_     = __builtin_amdgcn_cvt_pk_fp8_f32(m.z, m.w, t_, true);
      pk[j] = t_;
    }
    *(int4*)&s_item[r][q*16] = (int4){pk[0], pk[1], pk[2], pk[3]};
    pg += __shfl_xor(pg, 1);
    pg += __shfl_xor(pg, 2);
    if (q == 0) s_pg[r] = pg + cu[b];
    int i2 = tid >> 7, col = tid & 127;
    int bb = b0 + i2; if (bb >= Bsz) bb = Bsz - 1;
    s_xu[i2][col] = Xu[(long)bb*128 + col];
  }
  __syncthreads();

  // ---- G1: D[col128][pair64] fp8, K=64; +Xu, relu -> s_h1 (2 col-chunks) ----
  #pragma unroll
  for (int mt = 0; mt < 2; mt++){
    f32x4 acc[4];   // [nt] — 16 VGPR live
    #pragma unroll
    for (int nt = 0; nt < 4; nt++) acc[nt] = (f32x4){0.f, 0.f, 0.f, 0.f};
    #pragma unroll
    for (int ks = 0; ks < 2; ks++){
      long af = *(const long*)&W1iT[((w*2 + mt)*16 + lr)*64 + ks*32 + lg*8];
      #pragma unroll
      for (int nt = 0; nt < 4; nt++){
        long bf_ = *(const long*)&s_item[nt*16 + lr][ks*32 + lg*8];
        acc[nt] = __builtin_amdgcn_mfma_f32_16x16x32_fp8_fp8(af, bf_, acc[nt], 0, 0, 0);
      }
    }
    int colb = (w*2 + mt)*16 + lg*4;
    #pragma unroll
    for (int nt = 0; nt < 4; nt++){
      int pair = nt*16 + lr;
      int bl = (p0 + pair >= thr) ? 1 : 0;
      float4 xv = *(const float4*)&s_xu[bl][colb];
      float v0 = acc[nt][0] + xv.x; v0 = v0 > 0.f ? v0 : 0.f;
      float v1 = acc[nt][1] + xv.y; v1 = v1 > 0.f ? v1 : 0.f;
      float v2 = acc[nt][2] + xv.z; v2 = v2 > 0.f ? v2 : 0.f;
      float v3 = acc[nt][3] + xv.w; v3 = v3 > 0.f ? v3 : 0.f;
      int t_ = __builtin_amdgcn_cvt_pk_fp8_f32(v0, v1, 0, false);
      t_     = __builtin_amdgcn_cvt_pk_fp8_f32(v2, v3, t_, true);
      *(int*)&s_h1[pair][colb] = t_;
    }
  }
  __syncthreads();

  // ---- G2: D[col64][pair64] fp8, K=128; +b2, relu -> s_h2 ----
  {
    f32x4 acc[4];   // [nt]
    #pragma unroll
    for (int nt = 0; nt < 4; nt++) acc[nt] = (f32x4){0.f, 0.f, 0.f, 0.f};
    #pragma unroll
    for (int ks = 0; ks < 4; ks++){
      long af = *(const long*)&W2T[(w*16 + lr)*128 + ks*32 + lg*8];
      #pragma unroll
      for (int nt = 0; nt < 4; nt++){
        long bf_ = *(const long*)&s_h1[nt*16 + lr][ks*32 + lg*8];
        acc[nt] = __builtin_amdgcn_mfma_f32_16x16x32_fp8_fp8(af, bf_, acc[nt], 0, 0, 0);
      }
    }
    int colb = w*16 + lg*4;
    float4 b2v = *(const float4*)&b2[colb];
    #pragma unroll
    for (int nt = 0; nt < 4; nt++){
      int pair = nt*16 + lr;
      float v0 = acc[nt][0] + b2v.x; v0 = v0 > 0.f ? v0 : 0.f;
      float v1 = acc[nt][1] + b2v.y; v1 = v1 > 0.f ? v1 : 0.f;
      float v2 = acc[nt][2] + b2v.z; v2 = v2 > 0.f ? v2 : 0.f;
      float v3 = acc[nt][3] + b2v.w; v3 = v3 > 0.f ? v3 : 0.f;
      int t_ = __builtin_amdgcn_cvt_pk_fp8_f32(v0, v1, 0, false);
      t_     = __builtin_amdgcn_cvt_pk_fp8_f32(v2, v3, t_, true);
      *(int*)&s_h2[pair][colb] = t_;
    }
  }
  __syncthreads();

  // ---- G3: D[col32][pair16/wave] fp8, K=64; final dot + sigmoid ----
  {
    f32x4 acc[2];   // [mt]
    #pragma unroll
    for (int mt = 0; mt < 2; mt++) acc[mt] = (f32x4){0.f, 0.f, 0.f, 0.f};
    #pragma unroll
    for (int ks = 0; ks < 2; ks++){
      long bf_ = *(const long*)&s_h2[w*16 + lr][ks*32 + lg*8];
      #pragma unroll
      for (int mt = 0; mt < 2; mt++){
        long af = *(const long*)&W3T[(mt*16 + lr)*64 + ks*32 + lg*8];
        acc[mt] = __builtin_amdgcn_mfma_f32_16x16x32_fp8_fp8(af, bf_, acc[mt], 0, 0, 0);
      }
    }
    float t = 0.f;
    #pragma unroll
    for (int mt = 0; mt < 2; mt++){
      int colb = mt*16 + lg*4;
      float4 b3v = *(const float4*)&b3[colb];
      float4 wpv = *(const float4*)&Wp[64 + colb];
      float v0 = acc[mt][0] + b3v.x; v0 = v0 > 0.f ? v0 : 0.f;
      float v1 = acc[mt][1] + b3v.y; v1 = v1 > 0.f ? v1 : 0.f;
      float v2 = acc[mt][2] + b3v.z; v2 = v2 > 0.f ? v2 : 0.f;
      float v3 = acc[mt][3] + b3v.w; v3 = v3 > 0.f ? v3 : 0.f;
      t += v0*wpv.x + v1*wpv.y + v2*wpv.z + v3*wpv.w;
    }
    t += __shfl_xor(t, 16);
    t += __shfl_xor(t, 32);
    if (l < 16){
      int pair = w*16 + l;
      int p = p0 + pair;
      if (p < total){
        float z = t + s_pg[pair] + bp0;
        out[p] = 1.f / (1.f + __expf(-z));
      }
    }
  }
}

extern "C" void kernel_launch(void* const* d_in, const int* in_sizes, int n_in,
                              void* d_out, int out_size, void* d_ws, size_t ws_size,
                              hipStream_t stream)
{
  const int*   user   = (const int*)  d_in[0];
  const int*   item   = (const int*)  d_in[1];
  const float* Wu_gmf = (const float*)d_in[3];
  const float* bu_gmf = (const float*)d_in[4];
  const float* Wu_mlp = (const float*)d_in[5];
  const float* bu_mlp = (const float*)d_in[6];
  const float* Wi_gmf = (const float*)d_in[7];
  const float* bi_gmf = (const float*)d_in[8];
  const float* Wi_mlp = (const float*)d_in[9];
  const float* bi_mlp = (const float*)d_in[10];
  const float* W1     = (const float*)d_in[11];
  const float* b1     = (const float*)d_in[12];
  const float* W2     = (const float*)d_in[13];
  const float* b2     = (const float*)d_in[14];
  const float* W3     = (const float*)d_in[15];
  const float* b3     = (const float*)d_in[16];
  const float* Wp     = (const float*)d_in[17];
  const float* bp     = (const float*)d_in[18];

  int B     = in_sizes[0];            // 4096
  int total = in_sizes[1];            // 409600
  int N     = total / B;              // 100

  char* wsb = (char*)d_ws;
  unsigned char* W1iT = (unsigned char*)wsb;            // 8192
  unsigned char* W2T  = (unsigned char*)(wsb + 8192);   // 8192
  unsigned char* W3T  = (unsigned char*)(wsb + 16384);  // 2048
  float*         Xu   = (float*)(wsb + 18432);          // B*128
  float*         wup  = Xu  + (size_t)B * 128;          // B*64
  float*         cuv  = wup + (size_t)B * 64;           // B

  // one prep launch: B user-blocks + 144 transpose-blocks
  ncf_prep<<<B + 144, 128, 0, stream>>>(user, Wu_gmf, bu_gmf, Wu_mlp, bu_mlp,
                                        bi_gmf, bi_mlp, W1, b1, W2, W3, Wp,
                                        (unsigned char*)d_ws, Xu, wup, cuv, B);

  int nblk = (total + 63) / 64;       // 6400
  ncf_main<<<nblk, 256, 0, stream>>>(item, Wi_mlp, Wi_gmf,
      W1iT, W2T, W3T, b2, b3, Wp, bp, Xu, wup, cuv,
      (float*)d_out, N, total, B);
}